// Round 7
// baseline (132.599 us; speedup 1.0000x reference)
//
#include <hip/hip_runtime.h>
#include <hip/hip_bf16.h>
#include <math.h>

#define B_    16384
#define F_    26
#define E_    32
#define L_    50
#define CT_   13
#define D0_   909
#define D0P   928          // 29 * 32
#define D1_   512
#define D2_   256
#define SAMP  16           // samples per block
#define XPAD  936          // x0s row stride (elems); 1872B = 16B-aligned rows, ~2-way banks
#define H1PAD 520          // h1 row stride (elems); 1040B = 16B-aligned rows

typedef __bf16 bf16x8 __attribute__((ext_vector_type(8)));
typedef float f32x4 __attribute__((ext_vector_type(4)));

__device__ inline unsigned short f2b(float f) {
    union { __hip_bfloat16 h; unsigned short u; } v;
    v.h = __float2bfloat16(f);
    return v.u;
}

__device__ inline void gld_lds16(const void* g, void* l) {
    __builtin_amdgcn_global_load_lds(
        (const __attribute__((address_space(1))) unsigned int*)g,
        (__attribute__((address_space(3))) unsigned int*)l, 16, 0, 0);
}

// ---- weight conversion: fp32 -> bf16, pre-tiled into contiguous K-strips ----
// w2s layout: [29][512][32]  (strip ks holds W2[n][ks*32 .. ks*32+31], k>=909 zero)
// w3s layout: [16][256][32]
#define W2N (29 * D1_ * 32)      // 475136
#define W3N (16 * D2_ * 32)      // 131072
__global__ __launch_bounds__(256) void cvt_weights(
    const float* __restrict__ w2, const float* __restrict__ w3,
    __hip_bfloat16* __restrict__ o2, __hip_bfloat16* __restrict__ o3)
{
    int i = blockIdx.x * 256 + threadIdx.x;
    if (i < W2N) {
        int strip = i >> 14, rem = i & 16383;      // 512*32 = 16384
        int n = rem >> 5, kk = rem & 31;
        int k = strip * 32 + kk;
        float v = (k < D0_) ? w2[n * D0_ + k] : 0.f;
        o2[i] = __float2bfloat16(v);
    } else {
        int j = i - W2N;
        if (j < W3N) {
            int strip = j >> 13, rem = j & 8191;   // 256*32 = 8192
            int n = rem >> 5, kk = rem & 31;
            int k = strip * 32 + kk;
            o3[j] = __float2bfloat16(w3[n * D1_ + k]);
        }
    }
}

// ---- fully fused: embed(->LDS) + gemm1 + gemm2 + final dot + sigmoid ----
__global__ __launch_bounds__(512, 4) void fused_kernel(
    const int* __restrict__ oi, const float* __restrict__ ox,
    const int* __restrict__ i1, const float* __restrict__ x1,
    const int* __restrict__ i2, const float* __restrict__ x2,
    const float* __restrict__ ct, const float* __restrict__ wtab,
    const float* __restrict__ dtab,
    const __hip_bfloat16* __restrict__ w2s, const float* __restrict__ b2,
    const __hip_bfloat16* __restrict__ w3s, const float* __restrict__ b3,
    const float* __restrict__ w4, const float* __restrict__ b4,
    float* __restrict__ out)
{
    __shared__ __align__(16) unsigned short x0s[SAMP * XPAD];   // 29,952 B; h1 overlays later
    __shared__ __align__(16) unsigned short wst[D1_ * 32];      // 32,768 B weight strip
    __shared__ float parts[8][SAMP];
    __shared__ float wides[SAMP];

    const int tid  = threadIdx.x;
    const int lane = tid & 63;
    const int w    = tid >> 6;           // wave 0..7
    const int sbase = blockIdx.x * SAMP;
    const f32x4* dt4 = (const f32x4*)dtab;

    // ================= phase E: embed 16 samples into LDS =================
    {
        const int g = lane >> 3;         // gather group 0..7
        const int l = lane & 7;          // lane-in-group
        for (int ss = 0; ss < 2; ss++) {
            const int m = w * 2 + ss;    // row 0..15
            const int s = sbase + m;
            unsigned short* xrow = x0s + m * XPAD;

            // preload indices & scales (branchless)
            int koh[4]; float soh[4];
#pragma unroll
            for (int t = 0; t < 4; t++) {
                int f = g + 8 * t; bool v = (f < F_);
                koh[t] = v ? oi[s * F_ + f] : 0;
                soh[t] = v ? ox[s * F_ + f] : 0.f;
            }
            int k1[7], k2[7]; float sc1[7], sc2[7];
#pragma unroll
            for (int t = 0; t < 7; t++) {
                int j = g + 8 * t; bool v = (j < L_);
                k1[t]  = v ? i1[s * L_ + j] : 0;
                sc1[t] = v ? x1[s * L_ + j] : 0.f;
                k2[t]  = v ? i2[s * L_ + j] : 0;
                sc2[t] = v ? x2[s * L_ + j] : 0.f;
            }
            // issue all 18 row gathers
            f32x4 r1[7], r2[7], roh[4];
#pragma unroll
            for (int t = 0; t < 7; t++) r1[t] = dt4[(size_t)k1[t] * 8 + l];
#pragma unroll
            for (int t = 0; t < 7; t++) r2[t] = dt4[(size_t)k2[t] * 8 + l];
#pragma unroll
            for (int t = 0; t < 4; t++) roh[t] = dt4[(size_t)koh[t] * 8 + l];

            // one-hot consume -> LDS
#pragma unroll
            for (int t = 0; t < 4; t++) {
                int f = g + 8 * t;
                if (f < F_) {
                    ushort4 o;
                    o.x = f2b(roh[t].x * soh[t]); o.y = f2b(roh[t].y * soh[t]);
                    o.z = f2b(roh[t].z * soh[t]); o.w = f2b(roh[t].w * soh[t]);
                    *(ushort4*)(xrow + f * E_ + l * 4) = o;
                }
            }
            // bags accumulate
            f32x4 a1 = {0.f,0.f,0.f,0.f}, a2 = {0.f,0.f,0.f,0.f};
#pragma unroll
            for (int t = 0; t < 7; t++) {
                a1.x = fmaf(r1[t].x, sc1[t], a1.x); a1.y = fmaf(r1[t].y, sc1[t], a1.y);
                a1.z = fmaf(r1[t].z, sc1[t], a1.z); a1.w = fmaf(r1[t].w, sc1[t], a1.w);
                a2.x = fmaf(r2[t].x, sc2[t], a2.x); a2.y = fmaf(r2[t].y, sc2[t], a2.y);
                a2.z = fmaf(r2[t].z, sc2[t], a2.z); a2.w = fmaf(r2[t].w, sc2[t], a2.w);
            }
#pragma unroll
            for (int mm = 8; mm < 64; mm <<= 1) {
                a1.x += __shfl_xor(a1.x, mm); a1.y += __shfl_xor(a1.y, mm);
                a1.z += __shfl_xor(a1.z, mm); a1.w += __shfl_xor(a1.w, mm);
                a2.x += __shfl_xor(a2.x, mm); a2.y += __shfl_xor(a2.y, mm);
                a2.z += __shfl_xor(a2.z, mm); a2.w += __shfl_xor(a2.w, mm);
            }
            if (g == 0) {
                ushort4 o; o.x = f2b(a1.x); o.y = f2b(a1.y); o.z = f2b(a1.z); o.w = f2b(a1.w);
                *(ushort4*)(xrow + F_ * E_ + l * 4) = o;
            }
            if (g == 1) {
                ushort4 o; o.x = f2b(a2.x); o.y = f2b(a2.y); o.z = f2b(a2.z); o.w = f2b(a2.w);
                *(ushort4*)(xrow + F_ * E_ + E_ + l * 4) = o;
            }
            // ctns + zero pad: cols 896..929
            if (lane < 34) {
                float v = (lane < CT_) ? ct[s * CT_ + lane] : 0.f;
                xrow[F_ * E_ + 2 * E_ + lane] = f2b(v);
            }
            // wide (fp32 exact)
            float acc = 0.f;
#pragma unroll
            for (int t = lane; t < F_ + 2 * L_; t += 64) {
                int idx; float xv;
                if (t < F_)            { idx = oi[s * F_ + t];           xv = ox[s * F_ + t]; }
                else if (t < F_ + L_)  { int j = t - F_;      idx = i1[s * L_ + j]; xv = x1[s * L_ + j]; }
                else                   { int j = t - F_ - L_; idx = i2[s * L_ + j]; xv = x2[s * L_ + j]; }
                acc += wtab[idx] * xv;
            }
            for (int o = 32; o; o >>= 1) acc += __shfl_xor(acc, o);
            if (lane == 0) wides[m] = (float)E_ * acc;
        }
    }
    __syncthreads();

    // ================= phase G1: h1 = leaky(x0 @ W2^T + b2) =================
    const int fr = lane & 15;
    const int kg = lane >> 4;
    f32x4 acc1[4] = {};
    const int nb1 = w * 64;
    for (int ks = 0; ks < 29; ks++) {
        // stage W2 strip ks: contiguous 32KB, 8 waves x 4 rounds x 1KB
#pragma unroll
        for (int r = 0; r < 4; r++)
            gld_lds16(w2s + (size_t)ks * 16384 + w * 2048 + r * 512 + lane * 8,
                      (char*)wst + w * 4096 + r * 1024);
        __syncthreads();
        bf16x8 a = *(const bf16x8*)(x0s + fr * XPAD + ks * 32 + kg * 8);
#pragma unroll
        for (int nj = 0; nj < 4; nj++) {
            bf16x8 b = *(const bf16x8*)(wst + (nb1 + nj * 16 + fr) * 32 + kg * 8);
            acc1[nj] = __builtin_amdgcn_mfma_f32_16x16x32_bf16(a, b, acc1[nj], 0, 0, 0);
        }
        __syncthreads();
    }
    // write h1 (bf16) into LDS, overlaying x0s (dead after last barrier above)
    {
        const int m0 = kg * 4;
#pragma unroll
        for (int nj = 0; nj < 4; nj++) {
            int n = nb1 + nj * 16 + fr;
            float bb = b2[n];
#pragma unroll
            for (int r = 0; r < 4; r++) {
                float v = acc1[nj][r] + bb;
                v = (v >= 0.f) ? v : 0.01f * v;
                x0s[(m0 + r) * H1PAD + n] = f2b(v);
            }
        }
    }
    __syncthreads();

    // ================= phase G2: h2 = leaky(h1 @ W3^T + b3) =================
    f32x4 acc2[2] = {};
    const int nb2 = w * 32;
    for (int ks = 0; ks < 16; ks++) {
#pragma unroll
        for (int r = 0; r < 2; r++)
            gld_lds16(w3s + (size_t)ks * 8192 + w * 1024 + r * 512 + lane * 8,
                      (char*)wst + w * 2048 + r * 1024);
        __syncthreads();
        bf16x8 a = *(const bf16x8*)(x0s + fr * H1PAD + ks * 32 + kg * 8);
#pragma unroll
        for (int nj = 0; nj < 2; nj++) {
            bf16x8 b = *(const bf16x8*)(wst + (nb2 + nj * 16 + fr) * 32 + kg * 8);
            acc2[nj] = __builtin_amdgcn_mfma_f32_16x16x32_bf16(a, b, acc2[nj], 0, 0, 0);
        }
        __syncthreads();
    }

    // ================= phase F: out = sigmoid(h2 . w4 + b4 + wide) =================
    {
        float p[4] = {0.f, 0.f, 0.f, 0.f};
#pragma unroll
        for (int nj = 0; nj < 2; nj++) {
            int n = nb2 + nj * 16 + fr;
            float bb = b3[n];
            float wv = w4[n];
#pragma unroll
            for (int r = 0; r < 4; r++) {
                float v = acc2[nj][r] + bb;
                v = (v >= 0.f) ? v : 0.01f * v;
                p[r] = fmaf(v, wv, p[r]);
            }
        }
#pragma unroll
        for (int mm = 1; mm < 16; mm <<= 1) {
#pragma unroll
            for (int r = 0; r < 4; r++) p[r] += __shfl_xor(p[r], mm);
        }
        if (fr == 0) {
#pragma unroll
            for (int r = 0; r < 4; r++) parts[w][kg * 4 + r] = p[r];
        }
    }
    __syncthreads();
    if (tid < SAMP) {
        float x = 0.f;
#pragma unroll
        for (int ww = 0; ww < 8; ww++) x += parts[ww][tid];
        x += b4[0] + wides[tid];
        out[sbase + tid] = 1.f / (1.f + expf(-x));
    }
}

extern "C" void kernel_launch(void* const* d_in, const int* in_sizes, int n_in,
                              void* d_out, int out_size, void* d_ws, size_t ws_size,
                              hipStream_t stream) {
    const int*   oi  = (const int*)  d_in[0];
    const float* ox  = (const float*)d_in[1];
    const int*   i1  = (const int*)  d_in[2];
    const float* x1  = (const float*)d_in[3];
    const int*   i2  = (const int*)  d_in[4];
    const float* x2  = (const float*)d_in[5];
    const float* ct  = (const float*)d_in[6];
    const float* wt  = (const float*)d_in[7];
    const float* dt  = (const float*)d_in[8];
    const float* w2  = (const float*)d_in[9];
    const float* b2  = (const float*)d_in[10];
    const float* w3  = (const float*)d_in[11];
    const float* b3  = (const float*)d_in[12];
    const float* w4  = (const float*)d_in[13];
    const float* b4  = (const float*)d_in[14];
    float* out = (float*)d_out;

    char* ws = (char*)d_ws;
    __hip_bfloat16* w2s = (__hip_bfloat16*)(ws);                 // 475136*2 = 950,272 B
    __hip_bfloat16* w3s = (__hip_bfloat16*)(ws + 950272);        // 131072*2 = 262,144 B

    cvt_weights<<<(W2N + W3N + 255) / 256, 256, 0, stream>>>(w2, w3, w2s, w3s);
    fused_kernel<<<B_ / SAMP, 512, 0, stream>>>(oi, ox, i1, x1, i2, x2, ct, wt, dt,
                                                w2s, b2, w3s, b3, w4, b4, out);
}